// Round 1
// baseline (501.076 us; speedup 1.0000x reference)
//
#include <hip/hip_runtime.h>
#include <hip/hip_bf16.h>

// ---------------------------------------------------------------------------
// Head attention (B=512,T=128,C=1024,H=128), fp32 in/out.
//   k=idx@Wk, q=idx@Wq, v=idx@Wv
//   w = (q k^T) * sqrt(128), causal mask (valid t>=s), softmax over t (axis=1!)
//   out[t,h] = sum_s A[t,s] v[s,h]
// Strategy: split-fp32 (bf16 hi+lo, 3-term MFMA) for near-fp32 accuracy at
// MFMA rates. Kernel 0 preps W (transposed, split). Kernel 1 fused QKV GEMM
// (v stored transposed [b][h][t]). Kernel 2 per-batch attention.
// ---------------------------------------------------------------------------

typedef __attribute__((ext_vector_type(8))) __bf16 bf16x8;
typedef __attribute__((ext_vector_type(4))) float f32x4;
typedef __attribute__((ext_vector_type(4))) unsigned short u16x4;
typedef __attribute__((ext_vector_type(8))) unsigned short u16x8;

#define SQRT_H 11.313708498984761f

__device__ __forceinline__ void splitf(float a, unsigned short& hi, unsigned short& lo) {
    unsigned u = __float_as_uint(a);
    hi = (unsigned short)(u >> 16);                       // truncate to bf16
    float r = a - __uint_as_float(u & 0xFFFF0000u);       // exact residual
    lo = (unsigned short)(__float_as_uint(r) >> 16);      // next 8 mantissa bits
}

// ---------------------------------------------------------------------------
// Kernel 0: W [1024][128] fp32 (q,k,v) -> W2hi/W2lo [384][1024] bf16
// (row n = x*128+h, K-contiguous so GEMM B-frags are ds_read_b128-able)
// ---------------------------------------------------------------------------
__global__ __launch_bounds__(256) void prep_w(
    const float* __restrict__ Wq, const float* __restrict__ Wk, const float* __restrict__ Wv,
    unsigned short* __restrict__ W2hi, unsigned short* __restrict__ W2lo)
{
    __shared__ __align__(16) unsigned short thi[128][128];
    __shared__ __align__(16) unsigned short tlo[128][128];
    const float* W = (blockIdx.y == 0) ? Wq : (blockIdx.y == 1 ? Wk : Wv);
    const int c0 = blockIdx.x * 128;
    const int tid = threadIdx.x;
    #pragma unroll
    for (int it = 0; it < 16; ++it) {
        int chunk = tid + it * 256;            // 4096 float4 chunks: 128c x 32
        int cl = chunk >> 5, f4 = chunk & 31;
        float4 v = *(const float4*)(W + (size_t)(c0 + cl) * 128 + f4 * 4);
        unsigned short h, l;
        splitf(v.x, h, l); thi[cl][f4*4+0] = h; tlo[cl][f4*4+0] = l;
        splitf(v.y, h, l); thi[cl][f4*4+1] = h; tlo[cl][f4*4+1] = l;
        splitf(v.z, h, l); thi[cl][f4*4+2] = h; tlo[cl][f4*4+2] = l;
        splitf(v.w, h, l); thi[cl][f4*4+3] = h; tlo[cl][f4*4+3] = l;
    }
    __syncthreads();
    #pragma unroll
    for (int it = 0; it < 8; ++it) {
        int chunk = tid + it * 256;            // 2048 chunks: 128h x 16 slots
        int h = chunk >> 4, slot = chunk & 15;
        u16x8 vh, vl;
        #pragma unroll
        for (int e = 0; e < 8; ++e) { vh[e] = thi[slot*8+e][h]; vl[e] = tlo[slot*8+e][h]; }
        size_t off = (size_t)(blockIdx.y * 128 + h) * 1024 + c0 + slot * 8;
        *(u16x8*)(W2hi + off) = vh;
        *(u16x8*)(W2lo + off) = vl;
    }
}

// ---------------------------------------------------------------------------
// Kernel 1: fused QKV GEMM. grid = 512 batches * 3 ntiles (nt fast for L3
// reuse of the idx tile). Block 256 thr = 4 waves (2x2 of 64x64), BK=64.
// Split-fp32: acc += Ahi*Bhi + Alo*Bhi + Ahi*Blo.
// LDS XOR-swizzle (row&7)<<4 kills the stride-128B bank conflict (G4/T2).
// nt==2 writes v transposed: vT[b][h][t].
// ---------------------------------------------------------------------------
__global__ __launch_bounds__(256, 2) void qkv_gemm(
    const float* __restrict__ idx,
    const unsigned short* __restrict__ W2hi, const unsigned short* __restrict__ W2lo,
    float* __restrict__ qo, float* __restrict__ ko, float* __restrict__ vT)
{
    __shared__ __align__(16) char smem[65536];   // Ahi 0 | Alo 16K | Bhi 32K | Blo 48K
    const int tid  = threadIdx.x;
    const int lane = tid & 63;
    const int wid  = tid >> 6;
    const int wr = wid >> 1, wc = wid & 1;
    const int l16 = lane & 15, lgr = lane >> 4;
    const int bx = blockIdx.x;
    const int mt = bx / 3;          // batch (M-tile)
    const int nt = bx - mt * 3;     // 0=q 1=k 2=v

    f32x4 acc[4][4];
    #pragma unroll
    for (int m = 0; m < 4; ++m)
        #pragma unroll
        for (int n = 0; n < 4; ++n) acc[m][n] = (f32x4){0.f, 0.f, 0.f, 0.f};

    const float* Ag = idx + (size_t)mt * (128 * 1024);
    const unsigned short* Bhg = W2hi + (size_t)nt * 128 * 1024;
    const unsigned short* Blg = W2lo + (size_t)nt * 128 * 1024;

    for (int ks = 0; ks < 1024; ks += 64) {
        __syncthreads();   // previous iter's frag reads done before overwrite
        // stage A: 128 rows x 64 fp32 -> hi/lo bf16, swizzled
        #pragma unroll
        for (int it = 0; it < 8; ++it) {
            int chunk = tid + it * 256;          // 2048 chunks (128 x 16)
            int row = chunk >> 4, f4 = chunk & 15;
            float4 v = *(const float4*)(Ag + (size_t)row * 1024 + ks + f4 * 4);
            unsigned short h0,h1,h2,h3,l0,l1,l2,l3;
            splitf(v.x,h0,l0); splitf(v.y,h1,l1); splitf(v.z,h2,l2); splitf(v.w,h3,l3);
            u16x4 hv = {h0,h1,h2,h3}, lv = {l0,l1,l2,l3};
            int off = row * 128 + ((f4 * 8) ^ ((row & 7) << 4));
            *(u16x4*)(smem + off)         = hv;
            *(u16x4*)(smem + 16384 + off) = lv;
        }
        // stage B (already bf16): 128 rows x 64, 16B chunks, swizzled
        #pragma unroll
        for (int it = 0; it < 4; ++it) {
            int chunk = tid + it * 256;          // 1024 chunks (128 x 8)
            int row = chunk >> 3, slot = chunk & 7;
            size_t goff = (size_t)row * 1024 + ks + slot * 8;
            u16x8 bh = *(const u16x8*)(Bhg + goff);
            u16x8 bl = *(const u16x8*)(Blg + goff);
            int off = row * 128 + ((slot * 16) ^ ((row & 7) << 4));
            *(u16x8*)(smem + 32768 + off) = bh;
            *(u16x8*)(smem + 49152 + off) = bl;
        }
        __syncthreads();
        #pragma unroll
        for (int kk = 0; kk < 64; kk += 32) {
            const int kbyte = (kk + lgr * 8) * 2;
            bf16x8 ahi[4], alo[4], bhi[4], blo[4];
            #pragma unroll
            for (int m = 0; m < 4; ++m) {
                int row = wr * 64 + m * 16 + l16;
                int off = row * 128 + (kbyte ^ ((row & 7) << 4));
                ahi[m] = *(const bf16x8*)(smem + off);
                alo[m] = *(const bf16x8*)(smem + 16384 + off);
            }
            #pragma unroll
            for (int n = 0; n < 4; ++n) {
                int row = wc * 64 + n * 16 + l16;
                int off = row * 128 + (kbyte ^ ((row & 7) << 4));
                bhi[n] = *(const bf16x8*)(smem + 32768 + off);
                blo[n] = *(const bf16x8*)(smem + 49152 + off);
            }
            #pragma unroll
            for (int m = 0; m < 4; ++m)
                #pragma unroll
                for (int n = 0; n < 4; ++n) {
                    acc[m][n] = __builtin_amdgcn_mfma_f32_16x16x32_bf16(ahi[m], bhi[n], acc[m][n], 0, 0, 0);
                    acc[m][n] = __builtin_amdgcn_mfma_f32_16x16x32_bf16(alo[m], bhi[n], acc[m][n], 0, 0, 0);
                    acc[m][n] = __builtin_amdgcn_mfma_f32_16x16x32_bf16(ahi[m], blo[n], acc[m][n], 0, 0, 0);
                }
        }
    }
    // epilogue. C/D frag: col = l16, row = lgr*4 + j  [m89-verified]
    if (nt == 2) {
        float* outp = vT + (size_t)mt * (128 * 128);     // [h][t]
        #pragma unroll
        for (int m = 0; m < 4; ++m)
            #pragma unroll
            for (int n = 0; n < 4; ++n) {
                int t = wr * 64 + m * 16 + lgr * 4;
                int h = wc * 64 + n * 16 + l16;
                *(f32x4*)(outp + (size_t)h * 128 + t) = acc[m][n];  // 4 consecutive t
            }
    } else {
        float* outp = (nt == 0 ? qo : ko) + (size_t)mt * (128 * 128);  // [t][h]
        #pragma unroll
        for (int m = 0; m < 4; ++m)
            #pragma unroll
            for (int n = 0; n < 4; ++n)
                #pragma unroll
                for (int j = 0; j < 4; ++j) {
                    int t = wr * 64 + m * 16 + lgr * 4 + j;
                    int h = wc * 64 + n * 16 + l16;
                    outp[(size_t)t * 128 + h] = acc[m][n][j];
                }
    }
}

// ---------------------------------------------------------------------------
// Kernel 2: per-batch attention. 512 thr = 8 waves (2x4: 64t x 32n tiles).
// LDS phases (132.5 KB total):
//   [0,64K)   qhi|qlo  ->  S (fp32 [t][s])  ->  vhi|vlo (v/denom, [h][s])
//   [64,128K) khi|klo  ->  Ahi|Alo (exp values, [t][s])
//   scratch: colmax[512], colsum[512], invden[128]
// Softmax over t per column s; 1/denom folded into v staging.
// ---------------------------------------------------------------------------
__global__ __launch_bounds__(512, 2) void attn(
    const float* __restrict__ qg, const float* __restrict__ kg,
    const float* __restrict__ vTg, float* __restrict__ outg)
{
    __shared__ __align__(16) char smem[135680];
    float* S    = (float*)(smem);
    float* scrM = (float*)(smem + 131072);
    float* scrS = (float*)(smem + 133120);
    float* scrD = (float*)(smem + 135168);

    const int tid  = threadIdx.x;
    const int lane = tid & 63;
    const int wid  = tid >> 6;
    const int wr = wid >> 2, wc = wid & 3;
    const int l16 = lane & 15, lgr = lane >> 4;
    const int b = blockIdx.x;

    const float* qb = qg  + (size_t)b * 16384;
    const float* kb = kg  + (size_t)b * 16384;
    const float* vb = vTg + (size_t)b * 16384;

    // ---- stage q,k (fp32 -> hi/lo bf16, swizzled, row stride 256B) ----
    #pragma unroll
    for (int it = 0; it < 8; ++it) {
        int chunk = tid + it * 512;            // 4096 chunks (128 x 32)
        int row = chunk >> 5, f4 = chunk & 31;
        float4 vq = *(const float4*)(qb + (size_t)row * 128 + f4 * 4);
        float4 vk = *(const float4*)(kb + (size_t)row * 128 + f4 * 4);
        unsigned short h0,h1,h2,h3,l0,l1,l2,l3;
        int off = row * 256 + ((f4 * 8) ^ ((row & 7) << 4));
        splitf(vq.x,h0,l0); splitf(vq.y,h1,l1); splitf(vq.z,h2,l2); splitf(vq.w,h3,l3);
        *(u16x4*)(smem + off)         = (u16x4){h0,h1,h2,h3};
        *(u16x4*)(smem + 32768 + off) = (u16x4){l0,l1,l2,l3};
        splitf(vk.x,h0,l0); splitf(vk.y,h1,l1); splitf(vk.z,h2,l2); splitf(vk.w,h3,l3);
        *(u16x4*)(smem + 65536 + off) = (u16x4){h0,h1,h2,h3};
        *(u16x4*)(smem + 98304 + off) = (u16x4){l0,l1,l2,l3};
    }
    __syncthreads();

    // ---- S = q k^T  (M=t, N=s, K=h), 3-term split ----
    f32x4 accs[4][2];
    #pragma unroll
    for (int m = 0; m < 4; ++m) { accs[m][0] = (f32x4){0.f,0.f,0.f,0.f}; accs[m][1] = (f32x4){0.f,0.f,0.f,0.f}; }
    #pragma unroll
    for (int kk = 0; kk < 128; kk += 32) {
        const int kbyte = (kk + lgr * 8) * 2;
        bf16x8 qh[4], ql[4], kh[2], kl[2];
        #pragma unroll
        for (int m = 0; m < 4; ++m) {
            int row = wr * 64 + m * 16 + l16;
            int off = row * 256 + (kbyte ^ ((row & 7) << 4));
            qh[m] = *(const bf16x8*)(smem + off);
            ql[m] = *(const bf16x8*)(smem + 32768 + off);
        }
        #pragma unroll
        for (int n = 0; n < 2; ++n) {
            int row = wc * 32 + n * 16 + l16;
            int off = row * 256 + (kbyte ^ ((row & 7) << 4));
            kh[n] = *(const bf16x8*)(smem + 65536 + off);
            kl[n] = *(const bf16x8*)(smem + 98304 + off);
        }
        #pragma unroll
        for (int m = 0; m < 4; ++m)
            #pragma unroll
            for (int n = 0; n < 2; ++n) {
                accs[m][n] = __builtin_amdgcn_mfma_f32_16x16x32_bf16(qh[m], kh[n], accs[m][n], 0, 0, 0);
                accs[m][n] = __builtin_amdgcn_mfma_f32_16x16x32_bf16(ql[m], kh[n], accs[m][n], 0, 0, 0);
                accs[m][n] = __builtin_amdgcn_mfma_f32_16x16x32_bf16(qh[m], kl[n], accs[m][n], 0, 0, 0);
            }
    }
    __syncthreads();   // all q/k reads done; region 0-64K becomes S

    // ---- write S scaled + masked (mask t<s -> -1e30) ----
    #pragma unroll
    for (int m = 0; m < 4; ++m)
        #pragma unroll
        for (int n = 0; n < 2; ++n)
            #pragma unroll
            for (int j = 0; j < 4; ++j) {
                int t = wr * 64 + m * 16 + lgr * 4 + j;
                int s = wc * 32 + n * 16 + l16;
                float val = accs[m][n][j] * SQRT_H;
                S[t * 128 + s] = (t >= s) ? val : -1e30f;
            }
    __syncthreads();

    // ---- column softmax over t (4 threads per column) ----
    const int scol = tid & 127;
    const int qtr  = tid >> 7;
    const int t0   = qtr * 32;
    float mloc = -1e30f;
    for (int t = t0; t < t0 + 32; ++t) mloc = fmaxf(mloc, S[t * 128 + scol]);
    scrM[tid] = mloc;
    __syncthreads();
    float mm = fmaxf(fmaxf(scrM[scol], scrM[128 + scol]), fmaxf(scrM[256 + scol], scrM[384 + scol]));
    float sum = 0.f;
    for (int t = t0; t < t0 + 32; ++t) {
        float e = __expf(S[t * 128 + scol] - mm);   // masked -> 0
        sum += e;
        unsigned short hi, lo; splitf(e, hi, lo);
        int off = t * 256 + ((scol * 2) ^ ((t & 7) << 4));
        *(unsigned short*)(smem + 65536 + off) = hi;   // Ahi over khi
        *(unsigned short*)(smem + 98304 + off) = lo;   // Alo over klo
    }
    scrS[tid] = sum;
    __syncthreads();
    if (tid < 128) {
        float d = scrS[tid] + scrS[128 + tid] + scrS[256 + tid] + scrS[384 + tid];
        scrD[tid] = 1.f / d;
    }
    __syncthreads();   // also: all S reads done; region 0-64K becomes v

    // ---- stage v^T (scaled by 1/denom[s]), [h][s] hi/lo ----
    #pragma unroll
    for (int it = 0; it < 8; ++it) {
        int chunk = tid + it * 512;
        int row = chunk >> 5, f4 = chunk & 31;      // row=h, col=s
        float4 vv = *(const float4*)(vb + (size_t)row * 128 + f4 * 4);
        vv.x *= scrD[f4 * 4 + 0]; vv.y *= scrD[f4 * 4 + 1];
        vv.z *= scrD[f4 * 4 + 2]; vv.w *= scrD[f4 * 4 + 3];
        unsigned short h0,h1,h2,h3,l0,l1,l2,l3;
        splitf(vv.x,h0,l0); splitf(vv.y,h1,l1); splitf(vv.z,h2,l2); splitf(vv.w,h3,l3);
        int off = row * 256 + ((f4 * 8) ^ ((row & 7) << 4));
        *(u16x4*)(smem + off)         = (u16x4){h0,h1,h2,h3};
        *(u16x4*)(smem + 32768 + off) = (u16x4){l0,l1,l2,l3};
    }
    __syncthreads();

    // ---- out = A v  (M=t, N=h, K=s), 3-term split ----
    f32x4 acco[4][2];
    #pragma unroll
    for (int m = 0; m < 4; ++m) { acco[m][0] = (f32x4){0.f,0.f,0.f,0.f}; acco[m][1] = (f32x4){0.f,0.f,0.f,0.f}; }
    #pragma unroll
    for (int kk = 0; kk < 128; kk += 32) {
        const int kbyte = (kk + lgr * 8) * 2;
        bf16x8 ah[4], al[4], vh[2], vl[2];
        #pragma unroll
        for (int m = 0; m < 4; ++m) {
            int row = wr * 64 + m * 16 + l16;
            int off = row * 256 + (kbyte ^ ((row & 7) << 4));
            ah[m] = *(const bf16x8*)(smem + 65536 + off);
            al[m] = *(const bf16x8*)(smem + 98304 + off);
        }
        #pragma unroll
        for (int n = 0; n < 2; ++n) {
            int row = wc * 32 + n * 16 + l16;
            int off = row * 256 + (kbyte ^ ((row & 7) << 4));
            vh[n] = *(const bf16x8*)(smem + off);
            vl[n] = *(const bf16x8*)(smem + 32768 + off);
        }
        #pragma unroll
        for (int m = 0; m < 4; ++m)
            #pragma unroll
            for (int n = 0; n < 2; ++n) {
                acco[m][n] = __builtin_amdgcn_mfma_f32_16x16x32_bf16(ah[m], vh[n], acco[m][n], 0, 0, 0);
                acco[m][n] = __builtin_amdgcn_mfma_f32_16x16x32_bf16(al[m], vh[n], acco[m][n], 0, 0, 0);
                acco[m][n] = __builtin_amdgcn_mfma_f32_16x16x32_bf16(ah[m], vl[n], acco[m][n], 0, 0, 0);
            }
    }
    float* ob = outg + (size_t)b * 16384;
    #pragma unroll
    for (int m = 0; m < 4; ++m)
        #pragma unroll
        for (int n = 0; n < 2; ++n)
            #pragma unroll
            for (int j = 0; j < 4; ++j) {
                int t = wr * 64 + m * 16 + lgr * 4 + j;
                int h = wc * 32 + n * 16 + l16;
                ob[(size_t)t * 128 + h] = acco[m][n][j];
            }
}

// ---------------------------------------------------------------------------
extern "C" void kernel_launch(void* const* d_in, const int* in_sizes, int n_in,
                              void* d_out, int out_size, void* d_ws, size_t ws_size,
                              hipStream_t stream) {
    const float* idx = (const float*)d_in[0];
    const float* Wk  = (const float*)d_in[1];   // setup order: idx, Wk, Wq, Wv
    const float* Wq  = (const float*)d_in[2];
    const float* Wv  = (const float*)d_in[3];
    float* out = (float*)d_out;

    char* ws = (char*)d_ws;
    float* qb = (float*)(ws);                          // 33.55 MB  [B*T][128]
    float* kb = (float*)(ws + 33554432);               // 33.55 MB  [B*T][128]
    float* vT = (float*)(ws + 67108864);               // 33.55 MB  [B][128h][128t]
    unsigned short* W2hi = (unsigned short*)(ws + 100663296);  // 768 KB
    unsigned short* W2lo = (unsigned short*)(ws + 101449728);  // 768 KB

    prep_w<<<dim3(8, 3), 256, 0, stream>>>(Wq, Wk, Wv, W2hi, W2lo);
    qkv_gemm<<<dim3(512 * 3), 256, 0, stream>>>(idx, W2hi, W2lo, qb, kb, vT);
    attn<<<dim3(512), 512, 0, stream>>>(qb, kb, vT, out);
}

// Round 6
// 499.725 us; speedup vs baseline: 1.0027x; 1.0027x over previous
//
#include <hip/hip_runtime.h>
#include <hip/hip_bf16.h>

// ---------------------------------------------------------------------------
// Head attention (B=512,T=128,C=1024,H=128), fp32 in/out.
//   k=idx@Wk, q=idx@Wq, v=idx@Wv
//   w = (q k^T) * sqrt(128), causal mask (valid t>=s), softmax over t (axis=1!)
//   out[t,h] = sum_s A[t,s] v[s,h]
// Split-fp32 (bf16 hi+lo, 3-term MFMA) everywhere.
// R2 kernel, fifth submission (broker timeouts R2-R5 — still unmeasured):
// qkv gets XCD-grouping swizzle; attn rewritten: 66KB LDS (2 blocks/CU),
// S in registers, shuffle softmax, q/v fragments from global, k->A region
// reuse in LDS.
// ---------------------------------------------------------------------------

typedef __attribute__((ext_vector_type(8))) __bf16 bf16x8;
typedef __attribute__((ext_vector_type(4))) float f32x4;
typedef __attribute__((ext_vector_type(4))) unsigned short u16x4;
typedef __attribute__((ext_vector_type(8))) unsigned short u16x8;

#define SQRT_H 11.313708498984761f

__device__ __forceinline__ void splitf(float a, unsigned short& hi, unsigned short& lo) {
    unsigned u = __float_as_uint(a);
    hi = (unsigned short)(u >> 16);                       // truncate to bf16
    float r = a - __uint_as_float(u & 0xFFFF0000u);       // exact residual
    lo = (unsigned short)(__float_as_uint(r) >> 16);      // next 8 mantissa bits
}

// ---------------------------------------------------------------------------
// Kernel 0: W [1024][128] fp32 (q,k,v) -> W2hi/W2lo [384][1024] bf16
// ---------------------------------------------------------------------------
__global__ __launch_bounds__(256) void prep_w(
    const float* __restrict__ Wq, const float* __restrict__ Wk, const float* __restrict__ Wv,
    unsigned short* __restrict__ W2hi, unsigned short* __restrict__ W2lo)
{
    __shared__ __align__(16) unsigned short thi[128][128];
    __shared__ __align__(16) unsigned short tlo[128][128];
    const float* W = (blockIdx.y == 0) ? Wq : (blockIdx.y == 1 ? Wk : Wv);
    const int c0 = blockIdx.x * 128;
    const int tid = threadIdx.x;
    #pragma unroll
    for (int it = 0; it < 16; ++it) {
        int chunk = tid + it * 256;            // 4096 float4 chunks: 128c x 32
        int cl = chunk >> 5, f4 = chunk & 31;
        float4 v = *(const float4*)(W + (size_t)(c0 + cl) * 128 + f4 * 4);
        unsigned short h, l;
        splitf(v.x, h, l); thi[cl][f4*4+0] = h; tlo[cl][f4*4+0] = l;
        splitf(v.y, h, l); thi[cl][f4*4+1] = h; tlo[cl][f4*4+1] = l;
        splitf(v.z, h, l); thi[cl][f4*4+2] = h; tlo[cl][f4*4+2] = l;
        splitf(v.w, h, l); thi[cl][f4*4+3] = h; tlo[cl][f4*4+3] = l;
    }
    __syncthreads();
    #pragma unroll
    for (int it = 0; it < 8; ++it) {
        int chunk = tid + it * 256;            // 2048 chunks: 128h x 16 slots
        int h = chunk >> 4, slot = chunk & 15;
        u16x8 vh, vl;
        #pragma unroll
        for (int e = 0; e < 8; ++e) { vh[e] = thi[slot*8+e][h]; vl[e] = tlo[slot*8+e][h]; }
        size_t off = (size_t)(blockIdx.y * 128 + h) * 1024 + c0 + slot * 8;
        *(u16x8*)(W2hi + off) = vh;
        *(u16x8*)(W2lo + off) = vl;
    }
}

// ---------------------------------------------------------------------------
// Kernel 1: fused QKV GEMM. 1536 blocks; XCD-grouping swizzle so the 3
// nt-blocks of one mt land in the same XCD chunk (1536 = 8*192, bijective).
// Block 256 thr = 4 waves (2x2 of 64x64), BK=64, 3-term split-fp32.
// ---------------------------------------------------------------------------
__global__ __launch_bounds__(256, 2) void qkv_gemm(
    const float* __restrict__ idx,
    const unsigned short* __restrict__ W2hi, const unsigned short* __restrict__ W2lo,
    float* __restrict__ qo, float* __restrict__ ko, float* __restrict__ vT)
{
    __shared__ __align__(16) char smem[65536];   // Ahi 0 | Alo 16K | Bhi 32K | Blo 48K
    const int tid  = threadIdx.x;
    const int lane = tid & 63;
    const int wid  = tid >> 6;
    const int wr = wid >> 1, wc = wid & 1;
    const int l16 = lane & 15, lgr = lane >> 4;
    // XCD swizzle: consecutive HW bids round-robin XCDs; map so logical
    // blocks {3mt, 3mt+1, 3mt+2} share one XCD's L2 (idx panel reuse).
    const int hw = blockIdx.x;                 // 0..1535
    const int logical = (hw & 7) * 192 + (hw >> 3);
    const int mt = logical / 3;
    const int nt = logical - mt * 3;           // 0=q 1=k 2=v

    f32x4 acc[4][4];
    #pragma unroll
    for (int m = 0; m < 4; ++m)
        #pragma unroll
        for (int n = 0; n < 4; ++n) acc[m][n] = (f32x4){0.f, 0.f, 0.f, 0.f};

    const float* Ag = idx + (size_t)mt * (128 * 1024);
    const unsigned short* Bhg = W2hi + (size_t)nt * 128 * 1024;
    const unsigned short* Blg = W2lo + (size_t)nt * 128 * 1024;

    for (int ks = 0; ks < 1024; ks += 64) {
        __syncthreads();   // previous iter's frag reads done before overwrite
        // stage A: 128 rows x 64 fp32 -> hi/lo bf16, swizzled
        #pragma unroll
        for (int it = 0; it < 8; ++it) {
            int chunk = tid + it * 256;          // 2048 chunks (128 x 16)
            int row = chunk >> 4, f4 = chunk & 15;
            float4 v = *(const float4*)(Ag + (size_t)row * 1024 + ks + f4 * 4);
            unsigned short h0,h1,h2,h3,l0,l1,l2,l3;
            splitf(v.x,h0,l0); splitf(v.y,h1,l1); splitf(v.z,h2,l2); splitf(v.w,h3,l3);
            u16x4 hv = {h0,h1,h2,h3}, lv = {l0,l1,l2,l3};
            int off = row * 128 + ((f4 * 8) ^ ((row & 7) << 4));
            *(u16x4*)(smem + off)         = hv;
            *(u16x4*)(smem + 16384 + off) = lv;
        }
        // stage B (already bf16): 128 rows x 64, 16B chunks, swizzled
        #pragma unroll
        for (int it = 0; it < 4; ++it) {
            int chunk = tid + it * 256;          // 1024 chunks (128 x 8)
            int row = chunk >> 3, slot = chunk & 7;
            size_t goff = (size_t)row * 1024 + ks + slot * 8;
            u16x8 bh = *(const u16x8*)(Bhg + goff);
            u16x8 bl = *(const u16x8*)(Blg + goff);
            int off = row * 128 + ((slot * 16) ^ ((row & 7) << 4));
            *(u16x8*)(smem + 32768 + off) = bh;
            *(u16x8*)(smem + 49152 + off) = bl;
        }
        __syncthreads();
        #pragma unroll
        for (int kk = 0; kk < 64; kk += 32) {
            const int kbyte = (kk + lgr * 8) * 2;
            bf16x8 ahi[4], alo[4], bhi[4], blo[4];
            #pragma unroll
            for (int m = 0; m < 4; ++m) {
                int row = wr * 64 + m * 16 + l16;
                int off = row * 128 + (kbyte ^ ((row & 7) << 4));
                ahi[m] = *(const bf16x8*)(smem + off);
                alo[m] = *(const bf16x8*)(smem + 16384 + off);
            }
            #pragma unroll
            for (int n = 0; n < 4; ++n) {
                int row = wc * 64 + n * 16 + l16;
                int off = row * 128 + (kbyte ^ ((row & 7) << 4));
                bhi[n] = *(const bf16x8*)(smem + 32768 + off);
                blo[n] = *(const bf16x8*)(smem + 49152 + off);
            }
            #pragma unroll
            for (int m = 0; m < 4; ++m)
                #pragma unroll
                for (int n = 0; n < 4; ++n) {
                    acc[m][n] = __builtin_amdgcn_mfma_f32_16x16x32_bf16(ahi[m], bhi[n], acc[m][n], 0, 0, 0);
                    acc[m][n] = __builtin_amdgcn_mfma_f32_16x16x32_bf16(alo[m], bhi[n], acc[m][n], 0, 0, 0);
                    acc[m][n] = __builtin_amdgcn_mfma_f32_16x16x32_bf16(ahi[m], blo[n], acc[m][n], 0, 0, 0);
                }
        }
    }
    // epilogue. C/D frag: col = l16, row = lgr*4 + j  [m89-verified]
    if (nt == 2) {
        float* outp = vT + (size_t)mt * (128 * 128);     // [h][t]
        #pragma unroll
        for (int m = 0; m < 4; ++m)
            #pragma unroll
            for (int n = 0; n < 4; ++n) {
                int t = wr * 64 + m * 16 + lgr * 4;
                int h = wc * 64 + n * 16 + l16;
                *(f32x4*)(outp + (size_t)h * 128 + t) = acc[m][n];  // 4 consecutive t
            }
    } else {
        float* outp = (nt == 0 ? qo : ko) + (size_t)mt * (128 * 128);  // [t][h]
        #pragma unroll
        for (int m = 0; m < 4; ++m)
            #pragma unroll
            for (int n = 0; n < 4; ++n)
                #pragma unroll
                for (int j = 0; j < 4; ++j) {
                    int t = wr * 64 + m * 16 + lgr * 4 + j;
                    int h = wc * 64 + n * 16 + l16;
                    outp[(size_t)t * 128 + h] = acc[m][n][j];
                }
    }
}

// ---------------------------------------------------------------------------
// Kernel 2: per-batch attention, 512 thr = 8 waves (2 wr x 4 wc: 64t x 32s).
// LDS 67.6 KB -> 2 blocks/CU:
//   [0,32K)+[32K,64K): k hi/lo (rows=s, 256B stride, XOR-swizzled)
//                      -> reused for A hi/lo after QK^T
//   [64K,+1K) colmax scratch, [+1K,+1K) colsum scratch
// S stays in registers (C/D frags); column softmax over t via shfl_xor(16,32)
// across lgr groups + 1KB cross-wave scratch. q and v frags come straight
// from global (fp32 -> in-reg split); 1/denom folded into the A write.
// ---------------------------------------------------------------------------
__global__ __launch_bounds__(512, 4) void attn(
    const float* __restrict__ qg, const float* __restrict__ kg,
    const float* __restrict__ vTg, float* __restrict__ outg)
{
    __shared__ __align__(16) char smem[67584];
    float* scrM = (float*)(smem + 65536);   // [wr*4+wc][32] = 256 floats
    float* scrS = (float*)(smem + 66560);   // [wr*4+wc][32]

    const int tid  = threadIdx.x;
    const int lane = tid & 63;
    const int wid  = tid >> 6;
    const int wr = wid >> 2, wc = wid & 3;
    const int l16 = lane & 15, lgr = lane >> 4;
    const int b = blockIdx.x;

    const float* qb = qg  + (size_t)b * 16384;   // [t][h]
    const float* kb = kg  + (size_t)b * 16384;   // [s][h]
    const float* vb = vTg + (size_t)b * 16384;   // [h][s]

    // ---- stage k hi/lo (rows = s, swizzled) ----
    #pragma unroll
    for (int it = 0; it < 8; ++it) {
        int chunk = tid + it * 512;            // 4096 chunks (128 rows x 32)
        int row = chunk >> 5, f4 = chunk & 31;
        float4 vk = *(const float4*)(kb + (size_t)row * 128 + f4 * 4);
        unsigned short h0,h1,h2,h3,l0,l1,l2,l3;
        splitf(vk.x,h0,l0); splitf(vk.y,h1,l1); splitf(vk.z,h2,l2); splitf(vk.w,h3,l3);
        int off = row * 256 + ((f4 * 8) ^ ((row & 7) << 4));
        *(u16x4*)(smem + off)         = (u16x4){h0,h1,h2,h3};
        *(u16x4*)(smem + 32768 + off) = (u16x4){l0,l1,l2,l3};
    }
    __syncthreads();

    // ---- S = q k^T  (M=t, N=s, K=h); q frags straight from global ----
    f32x4 accs[4][2];
    #pragma unroll
    for (int m = 0; m < 4; ++m) { accs[m][0] = (f32x4){0.f,0.f,0.f,0.f}; accs[m][1] = (f32x4){0.f,0.f,0.f,0.f}; }
    #pragma unroll
    for (int kk = 0; kk < 128; kk += 32) {
        const int kbyte = (kk + lgr * 8) * 2;
        bf16x8 kh[2], kl[2];
        #pragma unroll
        for (int n = 0; n < 2; ++n) {
            int row = wc * 32 + n * 16 + l16;
            int off = row * 256 + (kbyte ^ ((row & 7) << 4));
            kh[n] = *(const bf16x8*)(smem + off);
            kl[n] = *(const bf16x8*)(smem + 32768 + off);
        }
        #pragma unroll
        for (int m = 0; m < 4; ++m) {
            int trow = wr * 64 + m * 16 + l16;
            float4 a0 = *(const float4*)(qb + trow * 128 + kk + lgr * 8);
            float4 a1 = *(const float4*)(qb + trow * 128 + kk + lgr * 8 + 4);
            unsigned short hh[8], ll[8];
            splitf(a0.x,hh[0],ll[0]); splitf(a0.y,hh[1],ll[1]);
            splitf(a0.z,hh[2],ll[2]); splitf(a0.w,hh[3],ll[3]);
            splitf(a1.x,hh[4],ll[4]); splitf(a1.y,hh[5],ll[5]);
            splitf(a1.z,hh[6],ll[6]); splitf(a1.w,hh[7],ll[7]);
            u16x8 qh8 = {hh[0],hh[1],hh[2],hh[3],hh[4],hh[5],hh[6],hh[7]};
            u16x8 ql8 = {ll[0],ll[1],ll[2],ll[3],ll[4],ll[5],ll[6],ll[7]};
            bf16x8 qh = *(bf16x8*)&qh8, ql = *(bf16x8*)&ql8;
            #pragma unroll
            for (int n = 0; n < 2; ++n) {
                accs[m][n] = __builtin_amdgcn_mfma_f32_16x16x32_bf16(qh, kh[n], accs[m][n], 0, 0, 0);
                accs[m][n] = __builtin_amdgcn_mfma_f32_16x16x32_bf16(ql, kh[n], accs[m][n], 0, 0, 0);
                accs[m][n] = __builtin_amdgcn_mfma_f32_16x16x32_bf16(qh, kl[n], accs[m][n], 0, 0, 0);
            }
        }
    }
    __syncthreads();   // k reads done; [0,64K) becomes the A region

    // ---- scale + mask + column max (softmax axis = t) ----
    float cmax[2] = {-3e38f, -3e38f};
    #pragma unroll
    for (int m = 0; m < 4; ++m)
        #pragma unroll
        for (int n = 0; n < 2; ++n)
            #pragma unroll
            for (int j = 0; j < 4; ++j) {
                int t = wr * 64 + m * 16 + lgr * 4 + j;
                int s = wc * 32 + n * 16 + l16;
                float val = accs[m][n][j] * SQRT_H;
                val = (t >= s) ? val : -1e30f;
                accs[m][n][j] = val;
                cmax[n] = fmaxf(cmax[n], val);
            }
    #pragma unroll
    for (int n = 0; n < 2; ++n) {
        cmax[n] = fmaxf(cmax[n], __shfl_xor(cmax[n], 16));
        cmax[n] = fmaxf(cmax[n], __shfl_xor(cmax[n], 32));
    }
    if (lgr == 0) {
        scrM[(wr * 4 + wc) * 32 + l16]      = cmax[0];
        scrM[(wr * 4 + wc) * 32 + 16 + l16] = cmax[1];
    }
    __syncthreads();
    float mm[2];
    #pragma unroll
    for (int n = 0; n < 2; ++n)
        mm[n] = fmaxf(scrM[wc * 32 + n * 16 + l16], scrM[(4 + wc) * 32 + n * 16 + l16]);

    // ---- exp + column sum ----
    float csum[2] = {0.f, 0.f};
    #pragma unroll
    for (int m = 0; m < 4; ++m)
        #pragma unroll
        for (int n = 0; n < 2; ++n)
            #pragma unroll
            for (int j = 0; j < 4; ++j) {
                float e = __expf(accs[m][n][j] - mm[n]);
                accs[m][n][j] = e;
                csum[n] += e;
            }
    #pragma unroll
    for (int n = 0; n < 2; ++n) {
        csum[n] += __shfl_xor(csum[n], 16);
        csum[n] += __shfl_xor(csum[n], 32);
    }
    if (lgr == 0) {
        scrS[(wr * 4 + wc) * 32 + l16]      = csum[0];
        scrS[(wr * 4 + wc) * 32 + 16 + l16] = csum[1];
    }
    __syncthreads();
    float inv[2];
    #pragma unroll
    for (int n = 0; n < 2; ++n)
        inv[n] = 1.f / (scrS[wc * 32 + n * 16 + l16] + scrS[(4 + wc) * 32 + n * 16 + l16]);

    // ---- write A hi/lo (normalized) into LDS over the k region ----
    #pragma unroll
    for (int m = 0; m < 4; ++m)
        #pragma unroll
        for (int n = 0; n < 2; ++n)
            #pragma unroll
            for (int j = 0; j < 4; ++j) {
                int t = wr * 64 + m * 16 + lgr * 4 + j;
                int s = wc * 32 + n * 16 + l16;
                float a = accs[m][n][j] * inv[n];
                unsigned short hi, lo; splitf(a, hi, lo);
                int off = t * 256 + ((s * 2) ^ ((t & 7) << 4));
                *(unsigned short*)(smem + off)         = hi;
                *(unsigned short*)(smem + 32768 + off) = lo;
            }
    __syncthreads();

    // ---- out = A v  (M=t, N=h, K=s); v frags straight from global vT ----
    f32x4 acco[4][2];
    #pragma unroll
    for (int m = 0; m < 4; ++m) { acco[m][0] = (f32x4){0.f,0.f,0.f,0.f}; acco[m][1] = (f32x4){0.f,0.f,0.f,0.f}; }
    #pragma unroll
    for (int kk = 0; kk < 128; kk += 32) {
        const int kbyte = (kk + lgr * 8) * 2;
        bf16x8 vh[2], vl[2];
        #pragma unroll
        for (int n = 0; n < 2; ++n) {
            int hrow = wc * 32 + n * 16 + l16;
            float4 v0 = *(const float4*)(vb + hrow * 128 + kk + lgr * 8);
            float4 v1 = *(const float4*)(vb + hrow * 128 + kk + lgr * 8 + 4);
            unsigned short hh[8], ll[8];
            splitf(v0.x,hh[0],ll[0]); splitf(v0.y,hh[1],ll[1]);
            splitf(v0.z,hh[2],ll[2]); splitf(v0.w,hh[3],ll[3]);
            splitf(v1.x,hh[4],ll[4]); splitf(v1.y,hh[5],ll[5]);
            splitf(v1.z,hh[6],ll[6]); splitf(v1.w,hh[7],ll[7]);
            u16x8 vh8 = {hh[0],hh[1],hh[2],hh[3],hh[4],hh[5],hh[6],hh[7]};
            u16x8 vl8 = {ll[0],ll[1],ll[2],ll[3],ll[4],ll[5],ll[6],ll[7]};
            vh[n] = *(bf16x8*)&vh8; vl[n] = *(bf16x8*)&vl8;
        }
        #pragma unroll
        for (int m = 0; m < 4; ++m) {
            int arow = wr * 64 + m * 16 + l16;
            int off = arow * 256 + (kbyte ^ ((arow & 7) << 4));
            bf16x8 ah = *(const bf16x8*)(smem + off);
            bf16x8 al = *(const bf16x8*)(smem + 32768 + off);
            #pragma unroll
            for (int n = 0; n < 2; ++n) {
                acco[m][n] = __builtin_amdgcn_mfma_f32_16x16x32_bf16(ah, vh[n], acco[m][n], 0, 0, 0);
                acco[m][n] = __builtin_amdgcn_mfma_f32_16x16x32_bf16(al, vh[n], acco[m][n], 0, 0, 0);
                acco[m][n] = __builtin_amdgcn_mfma_f32_16x16x32_bf16(ah, vl[n], acco[m][n], 0, 0, 0);
            }
        }
    }
    float* ob = outg + (size_t)b * 16384;
    #pragma unroll
    for (int m = 0; m < 4; ++m)
        #pragma unroll
        for (int n = 0; n < 2; ++n)
            #pragma unroll
            for (int j = 0; j < 4; ++j) {
                int t = wr * 64 + m * 16 + lgr * 4 + j;
                int h = wc * 32 + n * 16 + l16;
                ob[(size_t)t * 128 + h] = acco[m][n][j];
            }
}

// ---------------------------------------------------------------------------
extern "C" void kernel_launch(void* const* d_in, const int* in_sizes, int n_in,
                              void* d_out, int out_size, void* d_ws, size_t ws_size,
                              hipStream_t stream) {
    const float* idx = (const float*)d_in[0];
    const float* Wk  = (const float*)d_in[1];   // setup order: idx, Wk, Wq, Wv
    const float* Wq  = (const float*)d_in[2];
    const float* Wv  = (const float*)d_in[3];
    float* out = (float*)d_out;

    char* ws = (char*)d_ws;
    float* qb = (float*)(ws);                          // 33.55 MB  [B*T][128]
    float* kb = (float*)(ws + 33554432);               // 33.55 MB  [B*T][128]
    float* vT = (float*)(ws + 67108864);               // 33.55 MB  [B][128h][128t]
    unsigned short* W2hi = (unsigned short*)(ws + 100663296);  // 768 KB
    unsigned short* W2lo = (unsigned short*)(ws + 101449728);  // 768 KB

    prep_w<<<dim3(8, 3), 256, 0, stream>>>(Wq, Wk, Wv, W2hi, W2lo);
    qkv_gemm<<<dim3(512 * 3), 256, 0, stream>>>(idx, W2hi, W2lo, qb, kb, vT);
    attn<<<dim3(512), 512, 0, stream>>>(qb, kb, vT, out);
}

// Round 13
// 495.619 us; speedup vs baseline: 1.0110x; 1.0083x over previous
//
#include <hip/hip_runtime.h>
#include <hip/hip_bf16.h>

// ---------------------------------------------------------------------------
// Head attention (B=512,T=128,C=1024,H=128), fp32 in/out.
//   k=idx@Wk, q=idx@Wq, v=idx@Wv
//   w = (q k^T) * sqrt(128), causal mask (valid t>=s), softmax over t (axis=1!)
//   out[t,h] = sum_s A[t,s] v[s,h]
// R7 kernel, seventh submission (R7/R9-R12 broker timeouts, R8 container
// failure — still unmeasured): fused QKV GEMM (BN=384, one block per batch,
// A split once, v 1-term), q/k stored packed u32 (bf16 hi|lo), v stored bf16
// -> attn has NO splitf. attn v3: k from global, A hi-only in LDS, PV
// single-term, 3 barriers.
// ---------------------------------------------------------------------------

typedef __attribute__((ext_vector_type(8))) __bf16 bf16x8;
typedef __attribute__((ext_vector_type(4))) float f32x4;
typedef __attribute__((ext_vector_type(4))) unsigned short u16x4;
typedef __attribute__((ext_vector_type(8))) unsigned short u16x8;
typedef __attribute__((ext_vector_type(4))) unsigned int u32x4;

#define SQRT_H 11.313708498984761f

__device__ __forceinline__ void splitf(float a, unsigned short& hi, unsigned short& lo) {
    unsigned u = __float_as_uint(a);
    hi = (unsigned short)(u >> 16);                       // truncate to bf16
    float r = a - __uint_as_float(u & 0xFFFF0000u);       // exact residual
    lo = (unsigned short)(__float_as_uint(r) >> 16);      // next 8 mantissa bits
}

__device__ __forceinline__ unsigned short bf16rne(float a) {
    unsigned u = __float_as_uint(a);
    return (unsigned short)((u + 0x7fffu + ((u >> 16) & 1u)) >> 16);
}

// ---------------------------------------------------------------------------
// Kernel 0: W [1024][128] fp32 (q,k,v) -> W2hi/W2lo [384][1024] bf16
// rows 0-127 = Wq^T, 128-255 = Wk^T, 256-383 = Wv^T (K-contiguous)
// ---------------------------------------------------------------------------
__global__ __launch_bounds__(256) void prep_w(
    const float* __restrict__ Wq, const float* __restrict__ Wk, const float* __restrict__ Wv,
    unsigned short* __restrict__ W2hi, unsigned short* __restrict__ W2lo)
{
    __shared__ __align__(16) unsigned short thi[128][128];
    __shared__ __align__(16) unsigned short tlo[128][128];
    const float* W = (blockIdx.y == 0) ? Wq : (blockIdx.y == 1 ? Wk : Wv);
    const int c0 = blockIdx.x * 128;
    const int tid = threadIdx.x;
    #pragma unroll
    for (int it = 0; it < 16; ++it) {
        int chunk = tid + it * 256;            // 4096 float4 chunks: 128c x 32
        int cl = chunk >> 5, f4 = chunk & 31;
        float4 v = *(const float4*)(W + (size_t)(c0 + cl) * 128 + f4 * 4);
        unsigned short h, l;
        splitf(v.x, h, l); thi[cl][f4*4+0] = h; tlo[cl][f4*4+0] = l;
        splitf(v.y, h, l); thi[cl][f4*4+1] = h; tlo[cl][f4*4+1] = l;
        splitf(v.z, h, l); thi[cl][f4*4+2] = h; tlo[cl][f4*4+2] = l;
        splitf(v.w, h, l); thi[cl][f4*4+3] = h; tlo[cl][f4*4+3] = l;
    }
    __syncthreads();
    #pragma unroll
    for (int it = 0; it < 8; ++it) {
        int chunk = tid + it * 256;            // 2048 chunks: 128h x 16 slots
        int h = chunk >> 4, slot = chunk & 15;
        u16x8 vh, vl;
        #pragma unroll
        for (int e = 0; e < 8; ++e) { vh[e] = thi[slot*8+e][h]; vl[e] = tlo[slot*8+e][h]; }
        size_t off = (size_t)(blockIdx.y * 128 + h) * 1024 + c0 + slot * 8;
        *(u16x8*)(W2hi + off) = vh;
        *(u16x8*)(W2lo + off) = vl;
    }
}

// ---------------------------------------------------------------------------
// Kernel 1: fused QKV GEMM. 512 blocks (one per batch), 512 thr = 8 waves
// (wr 0..1 x wc 0..3). BM=128, BN=384, BK=64. Output col = n*64 + wc*16 + l16
// so each wave owns 2 q-frags (3-term), 2 k-frags (3-term), 2 v-frags (1-term).
// LDS 112KB: Ahi|Alo (16K+16K) + Bhi (48K) + Blo (32K, q/k rows only).
// q,k written as packed u32 (hi | lo<<16); v written bf16 transposed [h][t].
// ---------------------------------------------------------------------------
__global__ __launch_bounds__(512, 2) void qkv_fused(
    const float* __restrict__ idx,
    const unsigned short* __restrict__ W2hi, const unsigned short* __restrict__ W2lo,
    unsigned int* __restrict__ qpk, unsigned int* __restrict__ kpk,
    unsigned short* __restrict__ vT)
{
    __shared__ __align__(16) char smem[114688];
    // Ahi 0 | Alo 16384 | Bhi 32768 (48K) | Blo 81920 (32K: rows 0..255)
    const int tid  = threadIdx.x;
    const int lane = tid & 63;
    const int wid  = tid >> 6;
    const int wr = wid >> 2, wc = wid & 3;
    const int l16 = lane & 15, lgr = lane >> 4;
    const int mt = blockIdx.x;

    f32x4 acc[4][6];
    #pragma unroll
    for (int m = 0; m < 4; ++m)
        #pragma unroll
        for (int n = 0; n < 6; ++n) acc[m][n] = (f32x4){0.f, 0.f, 0.f, 0.f};

    const float* Ag = idx + (size_t)mt * (128 * 1024);

    for (int ks = 0; ks < 1024; ks += 64) {
        __syncthreads();   // previous iter's frag reads done before overwrite
        // stage A: 128 rows x 64 fp32 -> hi/lo bf16, swizzled (4 iters)
        #pragma unroll
        for (int it = 0; it < 4; ++it) {
            int chunk = tid + it * 512;          // 2048 chunks (128 x 16)
            int row = chunk >> 4, f4 = chunk & 15;
            float4 v = *(const float4*)(Ag + (size_t)row * 1024 + ks + f4 * 4);
            unsigned short h0,h1,h2,h3,l0,l1,l2,l3;
            splitf(v.x,h0,l0); splitf(v.y,h1,l1); splitf(v.z,h2,l2); splitf(v.w,h3,l3);
            int off = row * 128 + ((f4 * 8) ^ ((row & 7) << 4));
            *(u16x4*)(smem + off)         = (u16x4){h0,h1,h2,h3};
            *(u16x4*)(smem + 16384 + off) = (u16x4){l0,l1,l2,l3};
        }
        // stage B: 384 rows x 64 bf16 (hi; lo only for rows<256), 6 iters
        #pragma unroll
        for (int it = 0; it < 6; ++it) {
            int chunk = tid + it * 512;          // 3072 chunks (384 x 8)
            int r = chunk >> 3, slot = chunk & 7;
            size_t goff = (size_t)r * 1024 + ks + slot * 8;
            u16x8 bh = *(const u16x8*)(W2hi + goff);
            int off = r * 128 + ((slot * 16) ^ ((r & 7) << 4));
            *(u16x8*)(smem + 32768 + off) = bh;
            if (r < 256) {
                u16x8 bl = *(const u16x8*)(W2lo + goff);
                *(u16x8*)(smem + 81920 + off) = bl;
            }
        }
        __syncthreads();
        #pragma unroll
        for (int kk = 0; kk < 64; kk += 32) {
            const int kbyte = (kk + lgr * 8) * 2;
            bf16x8 ahi[4], alo[4];
            #pragma unroll
            for (int m = 0; m < 4; ++m) {
                int row = wr * 64 + m * 16 + l16;
                int off = row * 128 + (kbyte ^ ((row & 7) << 4));
                ahi[m] = *(const bf16x8*)(smem + off);
                alo[m] = *(const bf16x8*)(smem + 16384 + off);
            }
            #pragma unroll
            for (int n = 0; n < 6; ++n) {
                int brow = n * 64 + wc * 16 + l16;
                int boff = brow * 128 + (kbyte ^ ((brow & 7) << 4));
                bf16x8 bh = *(const bf16x8*)(smem + 32768 + boff);
                if (n < 4) {
                    bf16x8 bl = *(const bf16x8*)(smem + 81920 + boff);
                    #pragma unroll
                    for (int m = 0; m < 4; ++m) {
                        acc[m][n] = __builtin_amdgcn_mfma_f32_16x16x32_bf16(ahi[m], bh, acc[m][n], 0, 0, 0);
                        acc[m][n] = __builtin_amdgcn_mfma_f32_16x16x32_bf16(alo[m], bh, acc[m][n], 0, 0, 0);
                        acc[m][n] = __builtin_amdgcn_mfma_f32_16x16x32_bf16(ahi[m], bl, acc[m][n], 0, 0, 0);
                    }
                } else {
                    #pragma unroll
                    for (int m = 0; m < 4; ++m)
                        acc[m][n] = __builtin_amdgcn_mfma_f32_16x16x32_bf16(ahi[m], bh, acc[m][n], 0, 0, 0);
                }
            }
        }
    }
    // epilogue. C/D frag: col = l16, row = lgr*4 + j  [m89-verified]
    // out col = n*64 + wc*16 + l16 -> proj p = n>>1, h = (n&1)*64 + wc*16 + l16
    #pragma unroll
    for (int m = 0; m < 4; ++m)
        #pragma unroll
        for (int n = 0; n < 6; ++n) {
            const int p = n >> 1;
            const int h = (n & 1) * 64 + wc * 16 + l16;
            const int t0 = wr * 64 + m * 16 + lgr * 4;
            if (p == 2) {
                u16x4 vv;
                #pragma unroll
                for (int j = 0; j < 4; ++j) vv[j] = bf16rne(acc[m][n][j]);
                *(u16x4*)(vT + (size_t)mt * 16384 + (size_t)h * 128 + t0) = vv;  // [h][t]
            } else {
                unsigned int* dst = (p == 0 ? qpk : kpk) + (size_t)mt * 16384;
                #pragma unroll
                for (int j = 0; j < 4; ++j) {
                    unsigned short hi, lo; splitf(acc[m][n][j], hi, lo);
                    dst[(size_t)(t0 + j) * 128 + h] = (unsigned)hi | ((unsigned)lo << 16);
                }
            }
        }
}

// ---------------------------------------------------------------------------
// Kernel 2: attention v3. 512 blocks x 512 thr = 8 waves (wr 0..1 x wc 0..3).
// q,k from global packed u32 (no splitf, just unpack); QK^T 3-term; S in regs;
// column softmax over t (shfl_xor 16/32 + cross-wr LDS scratch); A written
// hi-only bf16 (normalized) to 32KB swizzled LDS; PV single-term with v bf16
// direct from global. LDS 34.8KB. 3 barriers.
// ---------------------------------------------------------------------------
__global__ __launch_bounds__(512, 4) void attn(
    const unsigned int* __restrict__ qpk, const unsigned int* __restrict__ kpk,
    const unsigned short* __restrict__ vTg, float* __restrict__ outg)
{
    __shared__ __align__(16) char smem[34816];
    float* scrM = (float*)(smem + 32768);   // [8 waves][32]
    float* scrS = (float*)(smem + 33792);   // [8 waves][32]

    const int tid  = threadIdx.x;
    const int lane = tid & 63;
    const int wid  = tid >> 6;
    const int wr = wid >> 2, wc = wid & 3;
    const int l16 = lane & 15, lgr = lane >> 4;
    const int b = blockIdx.x;

    const unsigned int*   qb = qpk + (size_t)b * 16384;   // [t][h] packed
    const unsigned int*   kb = kpk + (size_t)b * 16384;   // [s][h] packed
    const unsigned short* vb = vTg + (size_t)b * 16384;   // [h][s] bf16

    // ---- S = q k^T  (M=t, N=s, K=h), 3-term, frags from global packed ----
    f32x4 accs[4][2];
    #pragma unroll
    for (int m = 0; m < 4; ++m) { accs[m][0] = (f32x4){0.f,0.f,0.f,0.f}; accs[m][1] = (f32x4){0.f,0.f,0.f,0.f}; }
    #pragma unroll
    for (int kk = 0; kk < 128; kk += 32) {
        const int h0 = kk + lgr * 8;
        bf16x8 kh[2], kl[2];
        #pragma unroll
        for (int n = 0; n < 2; ++n) {
            int srow = wc * 32 + n * 16 + l16;
            const unsigned int* kp = kb + srow * 128 + h0;
            u32x4 p0 = *(const u32x4*)kp, p1 = *(const u32x4*)(kp + 4);
            u16x8 hh, ll;
            #pragma unroll
            for (int e = 0; e < 4; ++e) {
                hh[e] = (unsigned short)p0[e];  ll[e] = (unsigned short)(p0[e] >> 16);
                hh[4+e] = (unsigned short)p1[e]; ll[4+e] = (unsigned short)(p1[e] >> 16);
            }
            kh[n] = *(bf16x8*)&hh; kl[n] = *(bf16x8*)&ll;
        }
        #pragma unroll
        for (int m = 0; m < 4; ++m) {
            int trow = wr * 64 + m * 16 + l16;
            const unsigned int* qp = qb + trow * 128 + h0;
            u32x4 p0 = *(const u32x4*)qp, p1 = *(const u32x4*)(qp + 4);
            u16x8 hh, ll;
            #pragma unroll
            for (int e = 0; e < 4; ++e) {
                hh[e] = (unsigned short)p0[e];  ll[e] = (unsigned short)(p0[e] >> 16);
                hh[4+e] = (unsigned short)p1[e]; ll[4+e] = (unsigned short)(p1[e] >> 16);
            }
            bf16x8 qh = *(bf16x8*)&hh, ql = *(bf16x8*)&ll;
            #pragma unroll
            for (int n = 0; n < 2; ++n) {
                accs[m][n] = __builtin_amdgcn_mfma_f32_16x16x32_bf16(qh, kh[n], accs[m][n], 0, 0, 0);
                accs[m][n] = __builtin_amdgcn_mfma_f32_16x16x32_bf16(ql, kh[n], accs[m][n], 0, 0, 0);
                accs[m][n] = __builtin_amdgcn_mfma_f32_16x16x32_bf16(qh, kl[n], accs[m][n], 0, 0, 0);
            }
        }
    }

    // ---- scale + mask + column max (softmax axis = t) ----
    float cmax[2] = {-3e38f, -3e38f};
    #pragma unroll
    for (int m = 0; m < 4; ++m)
        #pragma unroll
        for (int n = 0; n < 2; ++n)
            #pragma unroll
            for (int j = 0; j < 4; ++j) {
                int t = wr * 64 + m * 16 + lgr * 4 + j;
                int s = wc * 32 + n * 16 + l16;
                float val = accs[m][n][j] * SQRT_H;
                val = (t >= s) ? val : -1e30f;
                accs[m][n][j] = val;
                cmax[n] = fmaxf(cmax[n], val);
            }
    #pragma unroll
    for (int n = 0; n < 2; ++n) {
        cmax[n] = fmaxf(cmax[n], __shfl_xor(cmax[n], 16));
        cmax[n] = fmaxf(cmax[n], __shfl_xor(cmax[n], 32));
    }
    if (lgr == 0) {
        scrM[(wr * 4 + wc) * 32 + l16]      = cmax[0];
        scrM[(wr * 4 + wc) * 32 + 16 + l16] = cmax[1];
    }
    __syncthreads();
    float mm[2];
    #pragma unroll
    for (int n = 0; n < 2; ++n)
        mm[n] = fmaxf(scrM[wc * 32 + n * 16 + l16], scrM[(4 + wc) * 32 + n * 16 + l16]);

    // ---- exp + column sum ----
    float csum[2] = {0.f, 0.f};
    #pragma unroll
    for (int m = 0; m < 4; ++m)
        #pragma unroll
        for (int n = 0; n < 2; ++n)
            #pragma unroll
            for (int j = 0; j < 4; ++j) {
                float e = __expf(accs[m][n][j] - mm[n]);
                accs[m][n][j] = e;
                csum[n] += e;
            }
    #pragma unroll
    for (int n = 0; n < 2; ++n) {
        csum[n] += __shfl_xor(csum[n], 16);
        csum[n] += __shfl_xor(csum[n], 32);
    }
    if (lgr == 0) {
        scrS[(wr * 4 + wc) * 32 + l16]      = csum[0];
        scrS[(wr * 4 + wc) * 32 + 16 + l16] = csum[1];
    }
    __syncthreads();
    float inv[2];
    #pragma unroll
    for (int n = 0; n < 2; ++n)
        inv[n] = 1.f / (scrS[wc * 32 + n * 16 + l16] + scrS[(4 + wc) * 32 + n * 16 + l16]);

    // ---- write A hi-only bf16 (normalized) into LDS [128t][128s] swizzled ----
    #pragma unroll
    for (int m = 0; m < 4; ++m)
        #pragma unroll
        for (int n = 0; n < 2; ++n)
            #pragma unroll
            for (int j = 0; j < 4; ++j) {
                int t = wr * 64 + m * 16 + lgr * 4 + j;
                int s = wc * 32 + n * 16 + l16;
                unsigned short a = bf16rne(accs[m][n][j] * inv[n]);
                int off = t * 256 + ((s * 2) ^ ((t & 7) << 4));
                *(unsigned short*)(smem + off) = a;
            }
    __syncthreads();

    // ---- out = A v  (M=t, N=h, K=s), single-term, v bf16 from global ----
    f32x4 acco[4][2];
    #pragma unroll
    for (int m = 0; m < 4; ++m) { acco[m][0] = (f32x4){0.f,0.f,0.f,0.f}; acco[m][1] = (f32x4){0.f,0.f,0.f,0.f}; }
    #pragma unroll
    for (int kk = 0; kk < 128; kk += 32) {
        const int s0 = kk + lgr * 8;
        bf16x8 vh[2];
        #pragma unroll
        for (int n = 0; n < 2; ++n) {
            int hrow = wc * 32 + n * 16 + l16;
            vh[n] = *(const bf16x8*)(vb + hrow * 128 + s0);
        }
        #pragma unroll
        for (int m = 0; m < 4; ++m) {
            int arow = wr * 64 + m * 16 + l16;
            int off = arow * 256 + ((s0 * 2) ^ ((arow & 7) << 4));
            bf16x8 ah = *(const bf16x8*)(smem + off);
            #pragma unroll
            for (int n = 0; n < 2; ++n)
                acco[m][n] = __builtin_amdgcn_mfma_f32_16x16x32_bf16(ah, vh[n], acco[m][n], 0, 0, 0);
        }
    }
    float* ob = outg + (size_t)b * 16384;
    #pragma unroll
    for (int m = 0; m < 4; ++m)
        #pragma unroll
        for (int n = 0; n < 2; ++n)
            #pragma unroll
            for (int j = 0; j < 4; ++j) {
                int t = wr * 64 + m * 16 + lgr * 4 + j;
                int h = wc * 32 + n * 16 + l16;
                ob[(size_t)t * 128 + h] = acco[m][n][j];
            }
}

// ---------------------------------------------------------------------------
extern "C" void kernel_launch(void* const* d_in, const int* in_sizes, int n_in,
                              void* d_out, int out_size, void* d_ws, size_t ws_size,
                              hipStream_t stream) {
    const float* idx = (const float*)d_in[0];
    const float* Wk  = (const float*)d_in[1];   // setup order: idx, Wk, Wq, Wv
    const float* Wq  = (const float*)d_in[2];
    const float* Wv  = (const float*)d_in[3];
    float* out = (float*)d_out;

    char* ws = (char*)d_ws;
    unsigned int*   qpk  = (unsigned int*)(ws);                      // 33.55 MB
    unsigned int*   kpk  = (unsigned int*)(ws + 33554432);           // 33.55 MB
    unsigned short* vT   = (unsigned short*)(ws + 67108864);         // 16.78 MB
    unsigned short* W2hi = (unsigned short*)(ws + 83886080);         // 768 KB
    unsigned short* W2lo = (unsigned short*)(ws + 84672512);         // 768 KB

    prep_w<<<dim3(8, 3), 256, 0, stream>>>(Wq, Wk, Wv, W2hi, W2lo);
    qkv_fused<<<dim3(512), 512, 0, stream>>>(idx, W2hi, W2lo, qpk, kpk, vT);
    attn<<<dim3(512), 512, 0, stream>>>(qpk, kpk, vT, out);
}